// Round 16
// baseline (513.691 us; speedup 1.0000x reference)
//
#include <hip/hip_runtime.h>
#include <math.h>

#define NGRID 32768   // 32^3 latent grid points
#define NOUT  16384   // output queries
#define CCH   256     // latent channels
#define H1DIM 512     // hidden width layer 1
#define TE    32      // edges per block (one 32-edge tile)
#define NTHR  512     // 8 waves; wave w owns channel group w for the single tile

typedef _Float16 f16x8 __attribute__((ext_vector_type(8)));
typedef float    f32x16 __attribute__((ext_vector_type(16)));

__device__ __forceinline__ unsigned short f32_to_f16_bits(float v) {
    _Float16 h = (_Float16)v;
    return __builtin_bit_cast(unsigned short, h);
}
__device__ __forceinline__ float h2l(unsigned u) {
    return (float)__builtin_bit_cast(_Float16, (unsigned short)(u & 0xffff));
}
__device__ __forceinline__ float h2h(unsigned u) {
    return (float)__builtin_bit_cast(_Float16, (unsigned short)(u >> 16));
}

// gelu via tanh-form: x * sigmoid(2*sqrt(2/pi)*(x + 0.044715 x^3)).
__device__ __forceinline__ float gelu_fast(float x) {
    float x2 = x * x;
    float u  = x * fmaf(0.035677408f, x2, 0.7978845608f);
    float e  = __builtin_amdgcn_exp2f(u * -2.885390082f);   // exp(-2u)
    return x * __builtin_amdgcn_rcpf(1.0f + e);
}

// Pack W2 (512x256) and W3 (256x256) into 32x32x16 A-fragment order, f16.
// A[m=ch][k], frag lane l: m = l&31, k = ks*16 + (l>>5)*8 + j.
// Flat: [ks][g(8)][lane(64)][j(8)] ; ch = g*32 + (l&31).
__global__ __launch_bounds__(256) void gino_pack_kernel(
    const float* __restrict__ W2, const float* __restrict__ W3,
    unsigned short* __restrict__ W2F, unsigned short* __restrict__ W3F)
{
    int idx = blockIdx.x * 256 + threadIdx.x;
    if (idx < 32 * 8 * 64) {          // W2F: ks 0..31
        int l = idx & 63, g = (idx >> 6) & 7, ks = idx >> 9;
        int ch = g * 32 + (l & 31);
        int k0 = ks * 16 + (l >> 5) * 8;
        unsigned int u[4];
        #pragma unroll
        for (int p = 0; p < 4; ++p) {
            unsigned int lo = f32_to_f16_bits(W2[(k0 + 2 * p) * CCH + ch]);
            unsigned int hh = f32_to_f16_bits(W2[(k0 + 2 * p + 1) * CCH + ch]);
            u[p] = lo | (hh << 16);
        }
        *(uint4*)(W2F + idx * 8) = make_uint4(u[0], u[1], u[2], u[3]);
    } else if (idx < 32 * 8 * 64 + 16 * 8 * 64) {   // W3F: ks 0..15
        int i2 = idx - 32 * 8 * 64;
        int l = i2 & 63, g = (i2 >> 6) & 7, ks = i2 >> 9;
        int ch = g * 32 + (l & 31);
        int k0 = ks * 16 + (l >> 5) * 8;
        unsigned int u[4];
        #pragma unroll
        for (int p = 0; p < 4; ++p) {
            unsigned int lo = f32_to_f16_bits(W3[(k0 + 2 * p) * CCH + ch]);
            unsigned int hh = f32_to_f16_bits(W3[(k0 + 2 * p + 1) * CCH + ch]);
            u[p] = lo | (hh << 16);
        }
        *(uint4*)(W3F + i2 * 8) = make_uint4(u[0], u[1], u[2], u[3]);
    }
}

// Convert latent_embed (2*32768*256 f32) to f16; 8 elems/thread.
__global__ __launch_bounds__(256) void gino_embed_f16_kernel(
    const float* __restrict__ in, unsigned short* __restrict__ out)
{
    int i = (blockIdx.x * 256 + threadIdx.x) * 8;
    float4 a = *(const float4*)(in + i);
    float4 b = *(const float4*)(in + i + 4);
    unsigned u0 = (unsigned)f32_to_f16_bits(a.x) | ((unsigned)f32_to_f16_bits(a.y) << 16);
    unsigned u1 = (unsigned)f32_to_f16_bits(a.z) | ((unsigned)f32_to_f16_bits(a.w) << 16);
    unsigned u2 = (unsigned)f32_to_f16_bits(b.x) | ((unsigned)f32_to_f16_bits(b.y) << 16);
    unsigned u3 = (unsigned)f32_to_f16_bits(b.z) | ((unsigned)f32_to_f16_bits(b.w) << 16);
    *(uint4*)(out + i) = make_uint4(u0, u1, u2, u3);
}

template <int F16E>
__global__ __launch_bounds__(NTHR, 6) void gino_edge_kernel(
    const float* __restrict__ latent_embed,   // (2, 32768, 256) f32
    const unsigned short* __restrict__ fembed,// (2, 32768, 256) f16 (if F16E)
    const float* __restrict__ latent_queries,
    const float* __restrict__ output_queries,
    const int*   __restrict__ nb_index,
    const int*   __restrict__ out_index,
    const float* __restrict__ W1, const float* __restrict__ b1,
    const float* __restrict__ b2, const float* __restrict__ b3,
    const unsigned short* __restrict__ W2F,
    const unsigned short* __restrict__ W3F,
    const float* __restrict__ Wp,
    float* __restrict__ sums, float* __restrict__ cnt, int E)
{
    __shared__ __align__(16) unsigned char s_h1[TE * 256];  // 8KB  h1 chunk f16 swz
    __shared__ __align__(16) unsigned char s_h2[TE * 512];  // 16KB h2 f16 swz
    __shared__ float s_agg[TE][8];
    __shared__ float s_pm[TE][8];
    __shared__ int s_nb[TE], s_oi[TE], s_valid[TE];

    const int tid = threadIdx.x;
    const int e0  = blockIdx.x * TE;

    // ---- Phase 0 ----
    if (tid < TE * 8) ((float*)s_pm)[tid] = 0.0f;
    if (tid < TE) {
        int e     = e0 + tid;
        int valid = (e < E) ? 1 : 0;
        int ec    = valid ? e : (E - 1);
        int nb    = nb_index[ec];
        int oi    = out_index[ec];
        s_nb[tid] = nb; s_oi[tid] = oi; s_valid[tid] = valid;
        s_agg[tid][0] = latent_queries[nb * 3 + 0];
        s_agg[tid][1] = latent_queries[nb * 3 + 1];
        s_agg[tid][2] = latent_queries[nb * 3 + 2];
        s_agg[tid][3] = output_queries[oi * 3 + 0];
        s_agg[tid][4] = output_queries[oi * 3 + 1];
        s_agg[tid][5] = output_queries[oi * 3 + 2];
        if (valid) atomicAdd(&cnt[oi], 1.0f);
    }
    __syncthreads();

    const int l  = tid & 63;
    const int w  = tid >> 6;      // wave id 0..7 == channel group g
    const int le = l & 31;
    const int hi = l >> 5;
    const unsigned bsw1 = (unsigned)(le & 15) << 4;   // s_h1 rows 256B -> 16 slots
    const unsigned bsw2 = (unsigned)(le & 31) << 4;   // s_h2 rows 512B -> 32 slots

    f32x16 acc = {};   // single edge-tile accumulator (16 AGPR)

    // ---- Phases 1+2 over four 128-col K-chunks of h1 ----
    #pragma unroll
    for (int c = 0; c < 4; ++c) {
        // Batch-issue this chunk's 8 W2 A-fragments; complete under phase-1 VALU.
        const unsigned short* gw = W2F + (size_t)(c * 8) * 4096 + w * 512 + l * 8;
        f16x8 a[8];
        #pragma unroll
        for (int ks = 0; ks < 8; ++ks)
            a[ks] = *(const f16x8*)(gw + (size_t)ks * 4096);
        __builtin_amdgcn_sched_barrier(0);

        // Phase 1: h1 cols [c*128, c*128+128); lane owns 2 cols, wave owns 4 edges
        {
            const int col = c * 128 + l * 2;
            float w0[6], w1v[6];
            #pragma unroll
            for (int i = 0; i < 6; ++i) {
                float2 t2 = *(const float2*)(W1 + i * H1DIM + col);
                w0[i] = t2.x; w1v[i] = t2.y;
            }
            float2 bb = *(const float2*)(b1 + col);
            #pragma unroll
            for (int ee = 0; ee < 4; ++ee) {
                int e = w * 4 + ee;
                float v0 = bb.x, v1 = bb.y;
                #pragma unroll
                for (int i = 0; i < 6; ++i) {
                    float av = s_agg[e][i];
                    v0 = fmaf(av, w0[i], v0);
                    v1 = fmaf(av, w1v[i], v1);
                }
                unsigned u = (unsigned)f32_to_f16_bits(gelu_fast(v0)) |
                             ((unsigned)f32_to_f16_bits(gelu_fast(v1)) << 16);
                *(unsigned*)(s_h1 + e * 256 + (((unsigned)(l * 4)) ^ (((unsigned)(e & 15)) << 4))) = u;
            }
        }
        __syncthreads();

        // Phase 2: 8 K-steps, A in registers, single B read per step
        __builtin_amdgcn_s_setprio(1);
        #pragma unroll
        for (int ks = 0; ks < 8; ++ks) {
            f16x8 b = *(const f16x8*)(s_h1 + le * 256 +
                          (((unsigned)(ks * 32 + hi * 16)) ^ bsw1));
            acc = __builtin_amdgcn_mfma_f32_32x32x16_f16(a[ks], b, acc, 0, 0, 0);
        }
        __builtin_amdgcn_s_setprio(0);
        __syncthreads();   // s_h1 reads done before next chunk overwrites
    }

    // ---- W3 A-frags, first batch of 8; complete under the epilogue VALU ----
    const unsigned short* gw3 = W3F + w * 512 + l * 8;
    f16x8 a3h[8];
    #pragma unroll
    for (int ks = 0; ks < 8; ++ks)
        a3h[ks] = *(const f16x8*)(gw3 + (size_t)ks * 4096);
    __builtin_amdgcn_sched_barrier(0);

    // ---- Epilogue: h2 = gelu(acc + b2) -> s_h2 (acc dies here) ----
    {
        unsigned esw = (unsigned)(le & 31) << 4;
        #pragma unroll
        for (int q = 0; q < 4; ++q) {
            int ch0 = w * 32 + q * 8 + hi * 4;
            float4 bb = *(const float4*)(b2 + ch0);
            float v0 = acc[q * 4 + 0] + bb.x;
            float v1 = acc[q * 4 + 1] + bb.y;
            float v2 = acc[q * 4 + 2] + bb.z;
            float v3 = acc[q * 4 + 3] + bb.w;
            unsigned int u0 = f32_to_f16_bits(gelu_fast(v0)) |
                              ((unsigned)f32_to_f16_bits(gelu_fast(v1)) << 16);
            unsigned int u1 = f32_to_f16_bits(gelu_fast(v2)) |
                              ((unsigned)f32_to_f16_bits(gelu_fast(v3)) << 16);
            *(uint2*)(s_h2 + le * 512 + (((unsigned)(ch0 * 2)) ^ esw)) = make_uint2(u0, u1);
        }
    }
    __syncthreads();

    // ---- Phase 3: k = h2 @ W3 + b3, two 8-frag batches ----
    f32x16 kc = {};
    __builtin_amdgcn_s_setprio(1);
    #pragma unroll
    for (int ks = 0; ks < 8; ++ks) {
        f16x8 b = *(const f16x8*)(s_h2 + le * 512 +
                      (((unsigned)(ks * 32 + hi * 16)) ^ bsw2));
        kc = __builtin_amdgcn_mfma_f32_32x32x16_f16(a3h[ks], b, kc, 0, 0, 0);
    }
    __builtin_amdgcn_s_setprio(0);
    #pragma unroll
    for (int ks = 0; ks < 8; ++ks)   // reload batch 2 (ks 8..15)
        a3h[ks] = *(const f16x8*)(gw3 + (size_t)(8 + ks) * 4096);
    __builtin_amdgcn_sched_barrier(0);
    __builtin_amdgcn_s_setprio(1);
    #pragma unroll
    for (int ks = 0; ks < 8; ++ks) {
        f16x8 b = *(const f16x8*)(s_h2 + le * 512 +
                      (((unsigned)((8 + ks) * 32 + hi * 16)) ^ bsw2));
        kc = __builtin_amdgcn_mfma_f32_32x32x16_f16(a3h[ks], b, kc, 0, 0, 0);
    }
    __builtin_amdgcn_s_setprio(0);

    // ---- Phase 4: dot k with f and Wp; hi-fold; LDS atomics ----
    {
        int nb = s_nb[le];
        float pm[8] = {0.f, 0.f, 0.f, 0.f, 0.f, 0.f, 0.f, 0.f};
        #pragma unroll
        for (int q = 0; q < 4; ++q) {
            int ch0 = w * 32 + q * 8 + hi * 4;
            float4 bb = *(const float4*)(b3 + ch0);
            float kv0 = kc[q * 4 + 0] + bb.x;
            float kv1 = kc[q * 4 + 1] + bb.y;
            float kv2 = kc[q * 4 + 2] + bb.z;
            float kv3 = kc[q * 4 + 3] + bb.w;
            float4 f0, f1;
            if constexpr (F16E) {
                const unsigned short* fp = fembed + (size_t)nb * CCH;
                uint2 u0 = *(const uint2*)(fp + ch0);
                uint2 u1 = *(const uint2*)(fp + (size_t)NGRID * CCH + ch0);
                f0 = make_float4(h2l(u0.x), h2h(u0.x), h2l(u0.y), h2h(u0.y));
                f1 = make_float4(h2l(u1.x), h2h(u1.x), h2l(u1.y), h2h(u1.y));
            } else {
                const float* fp = latent_embed + (size_t)nb * CCH;
                f0 = *(const float4*)(fp + ch0);
                f1 = *(const float4*)(fp + (size_t)NGRID * CCH + ch0);
            }
            float4 wp0 = *(const float4*)(Wp + (ch0 + 0) * 4);
            float4 wp1 = *(const float4*)(Wp + (ch0 + 1) * 4);
            float4 wp2 = *(const float4*)(Wp + (ch0 + 2) * 4);
            float4 wp3 = *(const float4*)(Wp + (ch0 + 3) * 4);
            float t0 = kv0 * f0.x, t1 = kv1 * f0.y, t2v = kv2 * f0.z, t3 = kv3 * f0.w;
            pm[0] = fmaf(t0, wp0.x, fmaf(t1, wp1.x, fmaf(t2v, wp2.x, fmaf(t3, wp3.x, pm[0]))));
            pm[1] = fmaf(t0, wp0.y, fmaf(t1, wp1.y, fmaf(t2v, wp2.y, fmaf(t3, wp3.y, pm[1]))));
            pm[2] = fmaf(t0, wp0.z, fmaf(t1, wp1.z, fmaf(t2v, wp2.z, fmaf(t3, wp3.z, pm[2]))));
            pm[3] = fmaf(t0, wp0.w, fmaf(t1, wp1.w, fmaf(t2v, wp2.w, fmaf(t3, wp3.w, pm[3]))));
            float s0 = kv0 * f1.x, s1 = kv1 * f1.y, s2 = kv2 * f1.z, s3 = kv3 * f1.w;
            pm[4] = fmaf(s0, wp0.x, fmaf(s1, wp1.x, fmaf(s2, wp2.x, fmaf(s3, wp3.x, pm[4]))));
            pm[5] = fmaf(s0, wp0.y, fmaf(s1, wp1.y, fmaf(s2, wp2.y, fmaf(s3, wp3.y, pm[5]))));
            pm[6] = fmaf(s0, wp0.z, fmaf(s1, wp1.z, fmaf(s2, wp2.z, fmaf(s3, wp3.z, pm[6]))));
            pm[7] = fmaf(s0, wp0.w, fmaf(s1, wp1.w, fmaf(s2, wp2.w, fmaf(s3, wp3.w, pm[7]))));
        }
        #pragma unroll
        for (int v = 0; v < 8; ++v) pm[v] += __shfl_xor(pm[v], 32);
        if (hi == 0) {
            #pragma unroll
            for (int v = 0; v < 8; ++v) atomicAdd(&s_pm[le][v], pm[v]);
        }
    }
    __syncthreads();

    // ---- Drain: one global atomic per value slot ----
    if (tid < TE * 8) {
        int el = tid >> 3;
        int v  = tid & 7;
        if (s_valid[el]) {
            int b  = v >> 2;
            int oc = v & 3;
            atomicAdd(&sums[((size_t)b * NOUT + s_oi[el]) * 4 + oc], s_pm[el][v]);
        }
    }
}

__global__ __launch_bounds__(256) void gino_finalize_kernel(
    const float* __restrict__ sums,
    const float* __restrict__ cnt,
    const float* __restrict__ bp,
    float* __restrict__ out)
{
    int idx = blockIdx.x * 256 + threadIdx.x;
    if (idx >= 2 * NOUT * 4) return;
    int oc = idx & 3;
    int i  = (idx >> 2) & (NOUT - 1);
    float c = fmaxf(cnt[i], 1.0f);
    out[idx] = sums[idx] / c + bp[oc];
}

extern "C" void kernel_launch(void* const* d_in, const int* in_sizes, int n_in,
                              void* d_out, int out_size, void* d_ws, size_t ws_size,
                              hipStream_t stream) {
    const float* latent_embed   = (const float*)d_in[0];
    const float* latent_queries = (const float*)d_in[1];
    const float* output_queries = (const float*)d_in[2];
    const int*   nb_index       = (const int*)d_in[3];
    const int*   out_index      = (const int*)d_in[4];
    const float* W1 = (const float*)d_in[5];
    const float* b1 = (const float*)d_in[6];
    const float* W2 = (const float*)d_in[7];
    const float* b2 = (const float*)d_in[8];
    const float* W3 = (const float*)d_in[9];
    const float* b3 = (const float*)d_in[10];
    const float* Wp = (const float*)d_in[11];
    const float* bp = (const float*)d_in[12];

    const int E = in_sizes[3];

    // ws layout: sums(512K) | cnt(64K) | W2F(256K) | W3F(128K) | fembed(32M f16)
    float* sums = (float*)d_ws;
    float* cnt  = sums + 2 * NOUT * 4;
    unsigned short* W2F = (unsigned short*)(cnt + NOUT);
    unsigned short* W3F = W2F + 32 * 8 * 64 * 8;
    unsigned short* fembed = W3F + 16 * 8 * 64 * 8;
    const size_t base_bytes = (size_t)((char*)fembed - (char*)d_ws);
    const size_t femb_bytes = (size_t)2 * NGRID * CCH * 2;
    const bool use_f16 = ws_size >= base_bytes + femb_bytes;

    hipMemsetAsync(d_ws, 0, (size_t)(2 * NOUT * 4 + NOUT) * sizeof(float), stream);

    gino_pack_kernel<<<(32 * 8 * 64 + 16 * 8 * 64 + 255) / 256, 256, 0, stream>>>(
        W2, W3, W2F, W3F);

    int nblk = (E + TE - 1) / TE;
    if (use_f16) {
        gino_embed_f16_kernel<<<(2 * NGRID * CCH / 8 + 255) / 256, 256, 0, stream>>>(
            latent_embed, fembed);
        gino_edge_kernel<1><<<nblk, NTHR, 0, stream>>>(
            latent_embed, fembed, latent_queries, output_queries, nb_index, out_index,
            W1, b1, b2, b3, W2F, W3F, Wp, sums, cnt, E);
    } else {
        gino_edge_kernel<0><<<nblk, NTHR, 0, stream>>>(
            latent_embed, (const unsigned short*)nullptr, latent_queries, output_queries,
            nb_index, out_index, W1, b1, b2, b3, W2F, W3F, Wp, sums, cnt, E);
    }

    gino_finalize_kernel<<<(2 * NOUT * 4 + 255) / 256, 256, 0, stream>>>(
        sums, cnt, bp, (float*)d_out);
}

// Round 17
// 239.346 us; speedup vs baseline: 2.1462x; 2.1462x over previous
//
#include <hip/hip_runtime.h>
#include <math.h>

#define NGRID 32768   // 32^3 latent grid points
#define NOUT  16384   // output queries
#define CCH   256     // latent channels
#define H1DIM 512     // hidden width layer 1
#define TE    64      // edges per block
#define NTHR  512     // 8 waves

#define EMB_BLOCKS 8192   // blocks of the prep kernel doing f32->f16 embed convert

typedef _Float16 f16x8 __attribute__((ext_vector_type(8)));
typedef float    f32x16 __attribute__((ext_vector_type(16)));

__device__ __forceinline__ unsigned short f32_to_f16_bits(float v) {
    _Float16 h = (_Float16)v;
    return __builtin_bit_cast(unsigned short, h);
}
__device__ __forceinline__ float h2l(unsigned u) {
    return (float)__builtin_bit_cast(_Float16, (unsigned short)(u & 0xffff));
}
__device__ __forceinline__ float h2h(unsigned u) {
    return (float)__builtin_bit_cast(_Float16, (unsigned short)(u >> 16));
}

// gelu via tanh-form: x * sigmoid(2*sqrt(2/pi)*(x + 0.044715 x^3)).
// 8 VALU ops (native exp2 + rcp). |err vs exact erf-gelu| <= ~4e-4 abs.
__device__ __forceinline__ float gelu_fast(float x) {
    float x2 = x * x;
    float u  = x * fmaf(0.035677408f, x2, 0.7978845608f);
    float e  = __builtin_amdgcn_exp2f(u * -2.885390082f);   // exp(-2u)
    return x * __builtin_amdgcn_rcpf(1.0f + e);
}

// Fused prep: blocks [0, EMB_BLOCKS) convert latent_embed f32->f16 (8 elems/thr);
// blocks >= EMB_BLOCKS pack W2 (512x256) and W3 (256x256) into 32x32x16
// A-fragment order, f16. A[m=ch][k], lane l: m=l&31, k=ks*16+(l>>5)*8+j.
// Flat: [ks][g(8)][lane(64)][j(8)] ; ch = g*32 + (l&31).
__global__ __launch_bounds__(256) void gino_prep_kernel(
    const float* __restrict__ embed_in, unsigned short* __restrict__ embed_out,
    const float* __restrict__ W2, const float* __restrict__ W3,
    unsigned short* __restrict__ W2F, unsigned short* __restrict__ W3F,
    int do_embed)
{
    if (do_embed && blockIdx.x < EMB_BLOCKS) {
        int i = (blockIdx.x * 256 + threadIdx.x) * 8;
        float4 a = *(const float4*)(embed_in + i);
        float4 b = *(const float4*)(embed_in + i + 4);
        unsigned u0 = (unsigned)f32_to_f16_bits(a.x) | ((unsigned)f32_to_f16_bits(a.y) << 16);
        unsigned u1 = (unsigned)f32_to_f16_bits(a.z) | ((unsigned)f32_to_f16_bits(a.w) << 16);
        unsigned u2 = (unsigned)f32_to_f16_bits(b.x) | ((unsigned)f32_to_f16_bits(b.y) << 16);
        unsigned u3 = (unsigned)f32_to_f16_bits(b.z) | ((unsigned)f32_to_f16_bits(b.w) << 16);
        *(uint4*)(embed_out + i) = make_uint4(u0, u1, u2, u3);
        return;
    }
    int base = do_embed ? EMB_BLOCKS : 0;
    int idx = (blockIdx.x - base) * 256 + threadIdx.x;
    if (idx < 32 * 8 * 64) {          // W2F: ks 0..31
        int l = idx & 63, g = (idx >> 6) & 7, ks = idx >> 9;
        int ch = g * 32 + (l & 31);
        int k0 = ks * 16 + (l >> 5) * 8;
        unsigned int u[4];
        #pragma unroll
        for (int p = 0; p < 4; ++p) {
            unsigned int lo = f32_to_f16_bits(W2[(k0 + 2 * p) * CCH + ch]);
            unsigned int hh = f32_to_f16_bits(W2[(k0 + 2 * p + 1) * CCH + ch]);
            u[p] = lo | (hh << 16);
        }
        *(uint4*)(W2F + idx * 8) = make_uint4(u[0], u[1], u[2], u[3]);
    } else if (idx < 32 * 8 * 64 + 16 * 8 * 64) {   // W3F: ks 0..15
        int i2 = idx - 32 * 8 * 64;
        int l = i2 & 63, g = (i2 >> 6) & 7, ks = i2 >> 9;
        int ch = g * 32 + (l & 31);
        int k0 = ks * 16 + (l >> 5) * 8;
        unsigned int u[4];
        #pragma unroll
        for (int p = 0; p < 4; ++p) {
            unsigned int lo = f32_to_f16_bits(W3[(k0 + 2 * p) * CCH + ch]);
            unsigned int hh = f32_to_f16_bits(W3[(k0 + 2 * p + 1) * CCH + ch]);
            u[p] = lo | (hh << 16);
        }
        *(uint4*)(W3F + i2 * 8) = make_uint4(u[0], u[1], u[2], u[3]);
    }
}

template <int F16E>
__global__ __launch_bounds__(NTHR, 4) void gino_edge_kernel(
    const float* __restrict__ latent_embed,   // (2, 32768, 256) f32
    const unsigned short* __restrict__ fembed,// (2, 32768, 256) f16 (if F16E)
    const float* __restrict__ latent_queries, // (32768, 3)
    const float* __restrict__ output_queries, // (16384, 3)
    const int*   __restrict__ nb_index,
    const int*   __restrict__ out_index,
    const float* __restrict__ W1, const float* __restrict__ b1,
    const float* __restrict__ b2, const float* __restrict__ b3,
    const unsigned short* __restrict__ W2F,
    const unsigned short* __restrict__ W3F,
    const float* __restrict__ Wp,
    float* __restrict__ sums, float* __restrict__ cnt, int E)
{
    __shared__ __align__(16) unsigned char s_h1[TE * 256];  // h1 128-col chunk f16 swz (16KB)
    __shared__ __align__(16) unsigned char s_h2[TE * 512];  // h2 f16 swz (32KB)
    __shared__ float s_agg[TE][8];
    __shared__ float s_pm[TE][8];
    __shared__ int s_nb[TE], s_oi[TE], s_valid[TE];

    const int tid = threadIdx.x;
    const int e0  = blockIdx.x * TE;

    // ---- Phase 0 ----
    ((float*)s_pm)[tid] = 0.0f;
    if (tid < TE) {
        int e     = e0 + tid;
        int valid = (e < E) ? 1 : 0;
        int ec    = valid ? e : (E - 1);
        int nb    = nb_index[ec];
        int oi    = out_index[ec];
        s_nb[tid] = nb; s_oi[tid] = oi; s_valid[tid] = valid;
        s_agg[tid][0] = latent_queries[nb * 3 + 0];
        s_agg[tid][1] = latent_queries[nb * 3 + 1];
        s_agg[tid][2] = latent_queries[nb * 3 + 2];
        s_agg[tid][3] = output_queries[oi * 3 + 0];
        s_agg[tid][4] = output_queries[oi * 3 + 1];
        s_agg[tid][5] = output_queries[oi * 3 + 2];
        if (valid) atomicAdd(&cnt[oi], 1.0f);
    }
    __syncthreads();

    const int l  = tid & 63;
    const int w  = tid >> 6;      // wave id 0..7 == channel group g
    const int le = l & 31;
    const int hi = l >> 5;
    const unsigned bsw1 = (unsigned)(le & 15) << 4;   // s_h1 rows = 256B -> 16 slots
    const unsigned bsw2 = (unsigned)(le & 31) << 4;   // s_h2 rows = 512B -> 32 slots

    f32x16 acc0 = {}, acc1 = {};   // layer-2 accum: edge-tile 0 / edge-tile 1

    // ---- Phases 1+2 over four 128-col K-chunks of h1 ----
    #pragma unroll
    for (int c = 0; c < 4; ++c) {
        // Batch-issue this chunk's 8 A-fragments into VGPRs; they complete
        // under phase-1's VALU work. sched_barrier pins issue before phase 1.
        const unsigned short* gw = W2F + (size_t)(c * 8) * 4096 + w * 512 + l * 8;
        f16x8 a[8];
        #pragma unroll
        for (int ks = 0; ks < 8; ++ks)
            a[ks] = *(const f16x8*)(gw + (size_t)ks * 4096);
        __builtin_amdgcn_sched_barrier(0);

        // Phase 1: h1 cols [c*128, c*128+128) ; lane owns 2 cols, wave owns 8 edges
        {
            const int col = c * 128 + l * 2;
            float w0[6], w1v[6];
            #pragma unroll
            for (int i = 0; i < 6; ++i) {
                float2 t2 = *(const float2*)(W1 + i * H1DIM + col);
                w0[i] = t2.x; w1v[i] = t2.y;
            }
            float2 bb = *(const float2*)(b1 + col);
            #pragma unroll
            for (int ee = 0; ee < 8; ++ee) {
                int e = w * 8 + ee;
                float v0 = bb.x, v1 = bb.y;
                #pragma unroll
                for (int i = 0; i < 6; ++i) {
                    float av = s_agg[e][i];
                    v0 = fmaf(av, w0[i], v0);
                    v1 = fmaf(av, w1v[i], v1);
                }
                unsigned u = (unsigned)f32_to_f16_bits(gelu_fast(v0)) |
                             ((unsigned)f32_to_f16_bits(gelu_fast(v1)) << 16);
                *(unsigned*)(s_h1 + e * 256 + (((unsigned)(l * 4)) ^ (((unsigned)(e & 15)) << 4))) = u;
            }
        }
        __syncthreads();

        // Phase 2: 8 K-steps, A already in registers, B from swizzled LDS
        __builtin_amdgcn_s_setprio(1);
        #pragma unroll
        for (int ks = 0; ks < 8; ++ks) {
            f16x8 b0 = *(const f16x8*)(s_h1 + le * 256 +
                           (((unsigned)(ks * 32 + hi * 16)) ^ bsw1));
            f16x8 b1f = *(const f16x8*)(s_h1 + (32 + le) * 256 +
                           (((unsigned)(ks * 32 + hi * 16)) ^ bsw1));
            acc0 = __builtin_amdgcn_mfma_f32_32x32x16_f16(a[ks], b0,  acc0, 0, 0, 0);
            acc1 = __builtin_amdgcn_mfma_f32_32x32x16_f16(a[ks], b1f, acc1, 0, 0, 0);
        }
        __builtin_amdgcn_s_setprio(0);
        __syncthreads();   // s_h1 reads done before next chunk overwrites
    }

    // ---- Batch-issue all 16 W3 A-fragments; they complete under the epilogue ----
    const unsigned short* gw3 = W3F + w * 512 + l * 8;
    f16x8 a3[16];
    #pragma unroll
    for (int ks = 0; ks < 16; ++ks)
        a3[ks] = *(const f16x8*)(gw3 + (size_t)ks * 4096);
    __builtin_amdgcn_sched_barrier(0);

    // ---- Phase 2 epilogue: h2 = gelu(acc + b2) -> s_h2 ----
    // D: col=le (edge-in-tile), local ch = (reg&3)+8*(reg>>2)+4*hi
    #pragma unroll
    for (int t = 0; t < 2; ++t) {
        int erow = t * 32 + le;
        unsigned esw = (unsigned)(erow & 31) << 4;
        #pragma unroll
        for (int q = 0; q < 4; ++q) {
            int ch0 = w * 32 + q * 8 + hi * 4;
            float4 bb = *(const float4*)(b2 + ch0);
            float v0 = (t ? acc1[q * 4 + 0] : acc0[q * 4 + 0]) + bb.x;
            float v1 = (t ? acc1[q * 4 + 1] : acc0[q * 4 + 1]) + bb.y;
            float v2 = (t ? acc1[q * 4 + 2] : acc0[q * 4 + 2]) + bb.z;
            float v3 = (t ? acc1[q * 4 + 3] : acc0[q * 4 + 3]) + bb.w;
            unsigned int u0 = f32_to_f16_bits(gelu_fast(v0)) |
                              ((unsigned)f32_to_f16_bits(gelu_fast(v1)) << 16);
            unsigned int u1 = f32_to_f16_bits(gelu_fast(v2)) |
                              ((unsigned)f32_to_f16_bits(gelu_fast(v3)) << 16);
            *(uint2*)(s_h2 + erow * 512 + (((unsigned)(ch0 * 2)) ^ esw)) = make_uint2(u0, u1);
        }
    }
    __syncthreads();

    // ---- Phase 3: k = h2 @ W3 + b3 (k stays in registers), A in registers ----
    f32x16 kc0 = {}, kc1 = {};
    __builtin_amdgcn_s_setprio(1);
    #pragma unroll
    for (int ks = 0; ks < 16; ++ks) {
        f16x8 b0 = *(const f16x8*)(s_h2 + le * 512 +
                       (((unsigned)(ks * 32 + hi * 16)) ^ bsw2));
        f16x8 b1f = *(const f16x8*)(s_h2 + (32 + le) * 512 +
                       (((unsigned)(ks * 32 + hi * 16)) ^ bsw2));
        kc0 = __builtin_amdgcn_mfma_f32_32x32x16_f16(a3[ks], b0,  kc0, 0, 0, 0);
        kc1 = __builtin_amdgcn_mfma_f32_32x32x16_f16(a3[ks], b1f, kc1, 0, 0, 0);
    }
    __builtin_amdgcn_s_setprio(0);

    // ---- Phase 4: per edge-tile, dot k with f and Wp; hi-fold; LDS atomics ----
    #pragma unroll
    for (int t = 0; t < 2; ++t) {
        int e  = t * 32 + le;
        int nb = s_nb[e];
        float pm[8] = {0.f, 0.f, 0.f, 0.f, 0.f, 0.f, 0.f, 0.f};
        #pragma unroll
        for (int q = 0; q < 4; ++q) {
            int ch0 = w * 32 + q * 8 + hi * 4;
            float4 bb = *(const float4*)(b3 + ch0);
            float kv0 = (t ? kc1[q * 4 + 0] : kc0[q * 4 + 0]) + bb.x;
            float kv1 = (t ? kc1[q * 4 + 1] : kc0[q * 4 + 1]) + bb.y;
            float kv2 = (t ? kc1[q * 4 + 2] : kc0[q * 4 + 2]) + bb.z;
            float kv3 = (t ? kc1[q * 4 + 3] : kc0[q * 4 + 3]) + bb.w;
            float4 f0, f1;
            if constexpr (F16E) {
                const unsigned short* fp = fembed + (size_t)nb * CCH;
                uint2 u0 = *(const uint2*)(fp + ch0);
                uint2 u1 = *(const uint2*)(fp + (size_t)NGRID * CCH + ch0);
                f0 = make_float4(h2l(u0.x), h2h(u0.x), h2l(u0.y), h2h(u0.y));
                f1 = make_float4(h2l(u1.x), h2h(u1.x), h2l(u1.y), h2h(u1.y));
            } else {
                const float* fp = latent_embed + (size_t)nb * CCH;
                f0 = *(const float4*)(fp + ch0);
                f1 = *(const float4*)(fp + (size_t)NGRID * CCH + ch0);
            }
            float4 wp0 = *(const float4*)(Wp + (ch0 + 0) * 4);
            float4 wp1 = *(const float4*)(Wp + (ch0 + 1) * 4);
            float4 wp2 = *(const float4*)(Wp + (ch0 + 2) * 4);
            float4 wp3 = *(const float4*)(Wp + (ch0 + 3) * 4);
            float t0 = kv0 * f0.x, t1 = kv1 * f0.y, t2v = kv2 * f0.z, t3 = kv3 * f0.w;
            pm[0] = fmaf(t0, wp0.x, fmaf(t1, wp1.x, fmaf(t2v, wp2.x, fmaf(t3, wp3.x, pm[0]))));
            pm[1] = fmaf(t0, wp0.y, fmaf(t1, wp1.y, fmaf(t2v, wp2.y, fmaf(t3, wp3.y, pm[1]))));
            pm[2] = fmaf(t0, wp0.z, fmaf(t1, wp1.z, fmaf(t2v, wp2.z, fmaf(t3, wp3.z, pm[2]))));
            pm[3] = fmaf(t0, wp0.w, fmaf(t1, wp1.w, fmaf(t2v, wp2.w, fmaf(t3, wp3.w, pm[3]))));
            float s0 = kv0 * f1.x, s1 = kv1 * f1.y, s2 = kv2 * f1.z, s3 = kv3 * f1.w;
            pm[4] = fmaf(s0, wp0.x, fmaf(s1, wp1.x, fmaf(s2, wp2.x, fmaf(s3, wp3.x, pm[4]))));
            pm[5] = fmaf(s0, wp0.y, fmaf(s1, wp1.y, fmaf(s2, wp2.y, fmaf(s3, wp3.y, pm[5]))));
            pm[6] = fmaf(s0, wp0.z, fmaf(s1, wp1.z, fmaf(s2, wp2.z, fmaf(s3, wp3.z, pm[6]))));
            pm[7] = fmaf(s0, wp0.w, fmaf(s1, wp1.w, fmaf(s2, wp2.w, fmaf(s3, wp3.w, pm[7]))));
        }
        #pragma unroll
        for (int v = 0; v < 8; ++v) pm[v] += __shfl_xor(pm[v], 32);
        if (hi == 0) {
            #pragma unroll
            for (int v = 0; v < 8; ++v) atomicAdd(&s_pm[e][v], pm[v]);
        }
    }
    __syncthreads();

    // ---- Drain: one global atomic per thread ----
    {
        int el = tid >> 3;
        int v  = tid & 7;
        if (s_valid[el]) {
            int b  = v >> 2;
            int oc = v & 3;
            atomicAdd(&sums[((size_t)b * NOUT + s_oi[el]) * 4 + oc], s_pm[el][v]);
        }
    }
}

__global__ __launch_bounds__(256) void gino_finalize_kernel(
    const float* __restrict__ sums,
    const float* __restrict__ cnt,
    const float* __restrict__ bp,
    float* __restrict__ out)
{
    int idx = blockIdx.x * 256 + threadIdx.x;
    if (idx >= 2 * NOUT * 4) return;
    int oc = idx & 3;
    int i  = (idx >> 2) & (NOUT - 1);
    float c = fmaxf(cnt[i], 1.0f);
    out[idx] = sums[idx] / c + bp[oc];
}

extern "C" void kernel_launch(void* const* d_in, const int* in_sizes, int n_in,
                              void* d_out, int out_size, void* d_ws, size_t ws_size,
                              hipStream_t stream) {
    const float* latent_embed   = (const float*)d_in[0];
    const float* latent_queries = (const float*)d_in[1];
    const float* output_queries = (const float*)d_in[2];
    const int*   nb_index       = (const int*)d_in[3];
    const int*   out_index      = (const int*)d_in[4];
    const float* W1 = (const float*)d_in[5];
    const float* b1 = (const float*)d_in[6];
    const float* W2 = (const float*)d_in[7];
    const float* b2 = (const float*)d_in[8];
    const float* W3 = (const float*)d_in[9];
    const float* b3 = (const float*)d_in[10];
    const float* Wp = (const float*)d_in[11];
    const float* bp = (const float*)d_in[12];

    const int E = in_sizes[3];

    // ws layout: sums(512K) | cnt(64K) | W2F(256K) | W3F(128K) | fembed(32M f16)
    float* sums = (float*)d_ws;
    float* cnt  = sums + 2 * NOUT * 4;
    unsigned short* W2F = (unsigned short*)(cnt + NOUT);
    unsigned short* W3F = W2F + 32 * 8 * 64 * 8;
    unsigned short* fembed = W3F + 16 * 8 * 64 * 8;
    const size_t base_bytes = (size_t)((char*)fembed - (char*)d_ws);
    const size_t femb_bytes = (size_t)2 * NGRID * CCH * 2;
    const bool use_f16 = ws_size >= base_bytes + femb_bytes;

    hipMemsetAsync(d_ws, 0, (size_t)(2 * NOUT * 4 + NOUT) * sizeof(float), stream);

    const int pack_blocks = (32 * 8 * 64 + 16 * 8 * 64 + 255) / 256;
    int nblk = (E + TE - 1) / TE;
    if (use_f16) {
        gino_prep_kernel<<<EMB_BLOCKS + pack_blocks, 256, 0, stream>>>(
            latent_embed, fembed, W2, W3, W2F, W3F, 1);
        gino_edge_kernel<1><<<nblk, NTHR, 0, stream>>>(
            latent_embed, fembed, latent_queries, output_queries, nb_index, out_index,
            W1, b1, b2, b3, W2F, W3F, Wp, sums, cnt, E);
    } else {
        gino_prep_kernel<<<pack_blocks, 256, 0, stream>>>(
            latent_embed, (unsigned short*)W2F /*unused*/, W2, W3, W2F, W3F, 0);
        gino_edge_kernel<0><<<nblk, NTHR, 0, stream>>>(
            latent_embed, (const unsigned short*)nullptr, latent_queries, output_queries,
            nb_index, out_index, W1, b1, b2, b3, W2F, W3F, Wp, sums, cnt, E);
    }

    gino_finalize_kernel<<<(2 * NOUT * 4 + 255) / 256, 256, 0, stream>>>(
        sums, cnt, bp, (float*)d_out);
}

// Round 19
// 234.160 us; speedup vs baseline: 2.1938x; 1.0221x over previous
//
#include <hip/hip_runtime.h>
#include <math.h>

#define NGRID 32768   // 32^3 latent grid points
#define NOUT  16384   // output queries
#define CCH   256     // latent channels
#define H1DIM 512     // hidden width layer 1
#define TE    64      // edges per block
#define NTHR  512     // 8 waves

#define EMB_BLOCKS 8192   // blocks of the prep kernel doing f32->f16 embed convert

typedef _Float16 f16x2 __attribute__((ext_vector_type(2)));
typedef _Float16 f16x8 __attribute__((ext_vector_type(8)));
typedef float    f32x16 __attribute__((ext_vector_type(16)));

__device__ __forceinline__ unsigned short f32_to_f16_bits(float v) {
    _Float16 h = (_Float16)v;
    return __builtin_bit_cast(unsigned short, h);
}
__device__ __forceinline__ f16x2 u2h2(unsigned u) {
    return __builtin_bit_cast(f16x2, u);
}
__device__ __forceinline__ f16x2 pk_f16(float a, float b) {
    return __builtin_bit_cast(f16x2, __builtin_amdgcn_cvt_pkrtz(a, b));
}

// gelu via tanh-form: x * sigmoid(2*sqrt(2/pi)*(x + 0.044715 x^3)).
// 8 VALU ops (native exp2 + rcp). |err vs exact erf-gelu| <= ~4e-4 abs.
__device__ __forceinline__ float gelu_fast(float x) {
    float x2 = x * x;
    float u  = x * fmaf(0.035677408f, x2, 0.7978845608f);
    float e  = __builtin_amdgcn_exp2f(u * -2.885390082f);   // exp(-2u)
    return x * __builtin_amdgcn_rcpf(1.0f + e);
}

// Fused prep: blocks [0, EMB_BLOCKS) convert latent_embed f32->f16 (8 elems/thr);
// blocks >= EMB_BLOCKS pack W2 (512x256), W3 (256x256) into 32x32x16 A-fragment
// order and Wp (256x4) into channel-pair f16 quads.
// A[m=ch][k], lane l: m=l&31, k=ks*16+(l>>5)*8+j.
// WpF[c2][oc] = pack_f16(Wp[2*c2][oc], Wp[2*c2+1][oc]), c2 in [0,128).
__global__ __launch_bounds__(256) void gino_prep_kernel(
    const float* __restrict__ embed_in, unsigned short* __restrict__ embed_out,
    const float* __restrict__ W2, const float* __restrict__ W3,
    const float* __restrict__ Wp,
    unsigned short* __restrict__ W2F, unsigned short* __restrict__ W3F,
    unsigned int* __restrict__ WpF,
    int do_embed)
{
    if (do_embed && blockIdx.x < EMB_BLOCKS) {
        int i = (blockIdx.x * 256 + threadIdx.x) * 8;
        float4 a = *(const float4*)(embed_in + i);
        float4 b = *(const float4*)(embed_in + i + 4);
        unsigned u0 = (unsigned)f32_to_f16_bits(a.x) | ((unsigned)f32_to_f16_bits(a.y) << 16);
        unsigned u1 = (unsigned)f32_to_f16_bits(a.z) | ((unsigned)f32_to_f16_bits(a.w) << 16);
        unsigned u2 = (unsigned)f32_to_f16_bits(b.x) | ((unsigned)f32_to_f16_bits(b.y) << 16);
        unsigned u3 = (unsigned)f32_to_f16_bits(b.z) | ((unsigned)f32_to_f16_bits(b.w) << 16);
        *(uint4*)(embed_out + i) = make_uint4(u0, u1, u2, u3);
        return;
    }
    int base = do_embed ? EMB_BLOCKS : 0;
    int idx = (blockIdx.x - base) * 256 + threadIdx.x;
    if (idx < 32 * 8 * 64) {          // W2F: ks 0..31
        int l = idx & 63, g = (idx >> 6) & 7, ks = idx >> 9;
        int ch = g * 32 + (l & 31);
        int k0 = ks * 16 + (l >> 5) * 8;
        unsigned int u[4];
        #pragma unroll
        for (int p = 0; p < 4; ++p) {
            unsigned int lo = f32_to_f16_bits(W2[(k0 + 2 * p) * CCH + ch]);
            unsigned int hh = f32_to_f16_bits(W2[(k0 + 2 * p + 1) * CCH + ch]);
            u[p] = lo | (hh << 16);
        }
        *(uint4*)(W2F + idx * 8) = make_uint4(u[0], u[1], u[2], u[3]);
    } else if (idx < 32 * 8 * 64 + 16 * 8 * 64) {   // W3F: ks 0..15
        int i2 = idx - 32 * 8 * 64;
        int l = i2 & 63, g = (i2 >> 6) & 7, ks = i2 >> 9;
        int ch = g * 32 + (l & 31);
        int k0 = ks * 16 + (l >> 5) * 8;
        unsigned int u[4];
        #pragma unroll
        for (int p = 0; p < 4; ++p) {
            unsigned int lo = f32_to_f16_bits(W3[(k0 + 2 * p) * CCH + ch]);
            unsigned int hh = f32_to_f16_bits(W3[(k0 + 2 * p + 1) * CCH + ch]);
            u[p] = lo | (hh << 16);
        }
        *(uint4*)(W3F + i2 * 8) = make_uint4(u[0], u[1], u[2], u[3]);
    } else if (idx < 32 * 8 * 64 + 16 * 8 * 64 + 128) {   // WpF: 128 channel pairs
        int c2 = idx - (32 * 8 * 64 + 16 * 8 * 64);
        float4 r0 = *(const float4*)(Wp + (2 * c2 + 0) * 4);
        float4 r1 = *(const float4*)(Wp + (2 * c2 + 1) * 4);
        unsigned v0 = (unsigned)f32_to_f16_bits(r0.x) | ((unsigned)f32_to_f16_bits(r1.x) << 16);
        unsigned v1 = (unsigned)f32_to_f16_bits(r0.y) | ((unsigned)f32_to_f16_bits(r1.y) << 16);
        unsigned v2 = (unsigned)f32_to_f16_bits(r0.z) | ((unsigned)f32_to_f16_bits(r1.z) << 16);
        unsigned v3 = (unsigned)f32_to_f16_bits(r0.w) | ((unsigned)f32_to_f16_bits(r1.w) << 16);
        *(uint4*)(WpF + c2 * 4) = make_uint4(v0, v1, v2, v3);
    }
}

template <int F16E>
__global__ __launch_bounds__(NTHR, 4) void gino_edge_kernel(
    const float* __restrict__ latent_embed,   // (2, 32768, 256) f32
    const unsigned short* __restrict__ fembed,// (2, 32768, 256) f16 (if F16E)
    const float* __restrict__ latent_queries, // (32768, 3)
    const float* __restrict__ output_queries, // (16384, 3)
    const int*   __restrict__ nb_index,
    const int*   __restrict__ out_index,
    const float* __restrict__ W1, const float* __restrict__ b1,
    const float* __restrict__ b2, const float* __restrict__ b3,
    const unsigned short* __restrict__ W2F,
    const unsigned short* __restrict__ W3F,
    const float* __restrict__ Wp,
    const unsigned int* __restrict__ WpF,
    float* __restrict__ sums, float* __restrict__ cnt, int E)
{
    __shared__ __align__(16) unsigned char s_h1[TE * 256];  // h1 128-col chunk f16 swz (16KB)
    __shared__ __align__(16) unsigned char s_h2[TE * 512];  // h2 f16 swz (32KB)
    __shared__ float s_agg[TE][8];
    __shared__ float s_pm[TE][8];
    __shared__ int s_nb[TE], s_oi[TE], s_valid[TE];

    const int tid = threadIdx.x;
    const int e0  = blockIdx.x * TE;

    // ---- Phase 0 ----
    ((float*)s_pm)[tid] = 0.0f;
    if (tid < TE) {
        int e     = e0 + tid;
        int valid = (e < E) ? 1 : 0;
        int ec    = valid ? e : (E - 1);
        int nb    = nb_index[ec];
        int oi    = out_index[ec];
        s_nb[tid] = nb; s_oi[tid] = oi; s_valid[tid] = valid;
        s_agg[tid][0] = latent_queries[nb * 3 + 0];
        s_agg[tid][1] = latent_queries[nb * 3 + 1];
        s_agg[tid][2] = latent_queries[nb * 3 + 2];
        s_agg[tid][3] = output_queries[oi * 3 + 0];
        s_agg[tid][4] = output_queries[oi * 3 + 1];
        s_agg[tid][5] = output_queries[oi * 3 + 2];
        if (valid) atomicAdd(&cnt[oi], 1.0f);
    }
    __syncthreads();

    const int l  = tid & 63;
    const int w  = tid >> 6;      // wave id 0..7 == channel group g
    const int le = l & 31;
    const int hi = l >> 5;
    const unsigned bsw1 = (unsigned)(le & 15) << 4;   // s_h1 rows = 256B -> 16 slots
    const unsigned bsw2 = (unsigned)(le & 31) << 4;   // s_h2 rows = 512B -> 32 slots

    f32x16 acc0 = {}, acc1 = {};   // layer-2 accum: edge-tile 0 / edge-tile 1

    // ---- Phases 1+2 over four 128-col K-chunks of h1 ----
    #pragma unroll
    for (int c = 0; c < 4; ++c) {
        // Batch-issue this chunk's 8 A-fragments into VGPRs; they complete
        // under phase-1's VALU work. sched_barrier pins issue before phase 1.
        const unsigned short* gw = W2F + (size_t)(c * 8) * 4096 + w * 512 + l * 8;
        f16x8 a[8];
        #pragma unroll
        for (int ks = 0; ks < 8; ++ks)
            a[ks] = *(const f16x8*)(gw + (size_t)ks * 4096);
        __builtin_amdgcn_sched_barrier(0);

        // Phase 1: h1 cols [c*128, c*128+128) ; lane owns 2 cols, wave owns 8 edges
        {
            const int col = c * 128 + l * 2;
            float w0[6], w1v[6];
            #pragma unroll
            for (int i = 0; i < 6; ++i) {
                float2 t2 = *(const float2*)(W1 + i * H1DIM + col);
                w0[i] = t2.x; w1v[i] = t2.y;
            }
            float2 bb = *(const float2*)(b1 + col);
            #pragma unroll
            for (int ee = 0; ee < 8; ++ee) {
                int e = w * 8 + ee;
                float v0 = bb.x, v1 = bb.y;
                #pragma unroll
                for (int i = 0; i < 6; ++i) {
                    float av = s_agg[e][i];
                    v0 = fmaf(av, w0[i], v0);
                    v1 = fmaf(av, w1v[i], v1);
                }
                unsigned u = (unsigned)f32_to_f16_bits(gelu_fast(v0)) |
                             ((unsigned)f32_to_f16_bits(gelu_fast(v1)) << 16);
                *(unsigned*)(s_h1 + e * 256 + (((unsigned)(l * 4)) ^ (((unsigned)(e & 15)) << 4))) = u;
            }
        }
        __syncthreads();

        // Phase 2: 8 K-steps, A already in registers, B from swizzled LDS
        __builtin_amdgcn_s_setprio(1);
        #pragma unroll
        for (int ks = 0; ks < 8; ++ks) {
            f16x8 b0 = *(const f16x8*)(s_h1 + le * 256 +
                           (((unsigned)(ks * 32 + hi * 16)) ^ bsw1));
            f16x8 b1f = *(const f16x8*)(s_h1 + (32 + le) * 256 +
                           (((unsigned)(ks * 32 + hi * 16)) ^ bsw1));
            acc0 = __builtin_amdgcn_mfma_f32_32x32x16_f16(a[ks], b0,  acc0, 0, 0, 0);
            acc1 = __builtin_amdgcn_mfma_f32_32x32x16_f16(a[ks], b1f, acc1, 0, 0, 0);
        }
        __builtin_amdgcn_s_setprio(0);
        __syncthreads();   // s_h1 reads done before next chunk overwrites
    }

    // ---- Batch-issue all 16 W3 A-fragments; they complete under the epilogue ----
    const unsigned short* gw3 = W3F + w * 512 + l * 8;
    f16x8 a3[16];
    #pragma unroll
    for (int ks = 0; ks < 16; ++ks)
        a3[ks] = *(const f16x8*)(gw3 + (size_t)ks * 4096);
    __builtin_amdgcn_sched_barrier(0);

    // ---- Phase 2 epilogue: h2 = gelu(acc + b2) -> s_h2 ----
    // D: col=le (edge-in-tile), local ch = (reg&3)+8*(reg>>2)+4*hi
    #pragma unroll
    for (int t = 0; t < 2; ++t) {
        int erow = t * 32 + le;
        unsigned esw = (unsigned)(erow & 31) << 4;
        #pragma unroll
        for (int q = 0; q < 4; ++q) {
            int ch0 = w * 32 + q * 8 + hi * 4;
            float4 bb = *(const float4*)(b2 + ch0);
            float v0 = (t ? acc1[q * 4 + 0] : acc0[q * 4 + 0]) + bb.x;
            float v1 = (t ? acc1[q * 4 + 1] : acc0[q * 4 + 1]) + bb.y;
            float v2 = (t ? acc1[q * 4 + 2] : acc0[q * 4 + 2]) + bb.z;
            float v3 = (t ? acc1[q * 4 + 3] : acc0[q * 4 + 3]) + bb.w;
            unsigned int u0 = f32_to_f16_bits(gelu_fast(v0)) |
                              ((unsigned)f32_to_f16_bits(gelu_fast(v1)) << 16);
            unsigned int u1 = f32_to_f16_bits(gelu_fast(v2)) |
                              ((unsigned)f32_to_f16_bits(gelu_fast(v3)) << 16);
            *(uint2*)(s_h2 + erow * 512 + (((unsigned)(ch0 * 2)) ^ esw)) = make_uint2(u0, u1);
        }
    }
    __syncthreads();

    // ---- Phase 3: k = h2 @ W3 + b3 (k stays in registers), A in registers ----
    f32x16 kc0 = {}, kc1 = {};
    __builtin_amdgcn_s_setprio(1);
    #pragma unroll
    for (int ks = 0; ks < 16; ++ks) {
        f16x8 b0 = *(const f16x8*)(s_h2 + le * 512 +
                       (((unsigned)(ks * 32 + hi * 16)) ^ bsw2));
        f16x8 b1f = *(const f16x8*)(s_h2 + (32 + le) * 512 +
                       (((unsigned)(ks * 32 + hi * 16)) ^ bsw2));
        kc0 = __builtin_amdgcn_mfma_f32_32x32x16_f16(a3[ks], b0,  kc0, 0, 0, 0);
        kc1 = __builtin_amdgcn_mfma_f32_32x32x16_f16(a3[ks], b1f, kc1, 0, 0, 0);
    }
    __builtin_amdgcn_s_setprio(0);

    // ---- Phase 4: per edge-tile, pm[oc] = sum_c (k[c]*f[c])*Wp[c][oc] ----
    // F16E path: packed-f16 math. kf = pk_f16(kv)*f (v_pk_mul_f16), then
    // v_dot2_f32_f16 against channel-pair-packed WpF. f32 pm accumulators.
    #pragma unroll
    for (int t = 0; t < 2; ++t) {
        int e  = t * 32 + le;
        int nb = s_nb[e];
        float pm[8] = {0.f, 0.f, 0.f, 0.f, 0.f, 0.f, 0.f, 0.f};
        if constexpr (F16E) {
            const unsigned short* fp = fembed + (size_t)nb * CCH;
            #pragma unroll
            for (int q = 0; q < 4; ++q) {
                int ch0 = w * 32 + q * 8 + hi * 4;
                float4 bb = *(const float4*)(b3 + ch0);
                float kv0 = (t ? kc1[q * 4 + 0] : kc0[q * 4 + 0]) + bb.x;
                float kv1 = (t ? kc1[q * 4 + 1] : kc0[q * 4 + 1]) + bb.y;
                float kv2 = (t ? kc1[q * 4 + 2] : kc0[q * 4 + 2]) + bb.z;
                float kv3 = (t ? kc1[q * 4 + 3] : kc0[q * 4 + 3]) + bb.w;
                f16x2 k01 = pk_f16(kv0, kv1);
                f16x2 k23 = pk_f16(kv2, kv3);
                uint2 u0 = *(const uint2*)(fp + ch0);
                uint2 u1 = *(const uint2*)(fp + (size_t)NGRID * CCH + ch0);
                uint4 wpA = *(const uint4*)(WpF + (size_t)(ch0 >> 1) * 4);
                uint4 wpB = *(const uint4*)(WpF + (size_t)((ch0 >> 1) + 1) * 4);
                f16x2 kfa = k01 * u2h2(u0.x);
                f16x2 kfb = k23 * u2h2(u0.y);
                pm[0] = __builtin_amdgcn_fdot2(kfa, u2h2(wpA.x), pm[0], false);
                pm[0] = __builtin_amdgcn_fdot2(kfb, u2h2(wpB.x), pm[0], false);
                pm[1] = __builtin_amdgcn_fdot2(kfa, u2h2(wpA.y), pm[1], false);
                pm[1] = __builtin_amdgcn_fdot2(kfb, u2h2(wpB.y), pm[1], false);
                pm[2] = __builtin_amdgcn_fdot2(kfa, u2h2(wpA.z), pm[2], false);
                pm[2] = __builtin_amdgcn_fdot2(kfb, u2h2(wpB.z), pm[2], false);
                pm[3] = __builtin_amdgcn_fdot2(kfa, u2h2(wpA.w), pm[3], false);
                pm[3] = __builtin_amdgcn_fdot2(kfb, u2h2(wpB.w), pm[3], false);
                f16x2 kga = k01 * u2h2(u1.x);
                f16x2 kgb = k23 * u2h2(u1.y);
                pm[4] = __builtin_amdgcn_fdot2(kga, u2h2(wpA.x), pm[4], false);
                pm[4] = __builtin_amdgcn_fdot2(kgb, u2h2(wpB.x), pm[4], false);
                pm[5] = __builtin_amdgcn_fdot2(kga, u2h2(wpA.y), pm[5], false);
                pm[5] = __builtin_amdgcn_fdot2(kgb, u2h2(wpB.y), pm[5], false);
                pm[6] = __builtin_amdgcn_fdot2(kga, u2h2(wpA.z), pm[6], false);
                pm[6] = __builtin_amdgcn_fdot2(kgb, u2h2(wpB.z), pm[6], false);
                pm[7] = __builtin_amdgcn_fdot2(kga, u2h2(wpA.w), pm[7], false);
                pm[7] = __builtin_amdgcn_fdot2(kgb, u2h2(wpB.w), pm[7], false);
            }
        } else {
            #pragma unroll
            for (int q = 0; q < 4; ++q) {
                int ch0 = w * 32 + q * 8 + hi * 4;
                float4 bb = *(const float4*)(b3 + ch0);
                float kv0 = (t ? kc1[q * 4 + 0] : kc0[q * 4 + 0]) + bb.x;
                float kv1 = (t ? kc1[q * 4 + 1] : kc0[q * 4 + 1]) + bb.y;
                float kv2 = (t ? kc1[q * 4 + 2] : kc0[q * 4 + 2]) + bb.z;
                float kv3 = (t ? kc1[q * 4 + 3] : kc0[q * 4 + 3]) + bb.w;
                const float* fp = latent_embed + (size_t)nb * CCH;
                float4 f0 = *(const float4*)(fp + ch0);
                float4 f1 = *(const float4*)(fp + (size_t)NGRID * CCH + ch0);
                float4 wp0 = *(const float4*)(Wp + (ch0 + 0) * 4);
                float4 wp1 = *(const float4*)(Wp + (ch0 + 1) * 4);
                float4 wp2 = *(const float4*)(Wp + (ch0 + 2) * 4);
                float4 wp3 = *(const float4*)(Wp + (ch0 + 3) * 4);
                float t0 = kv0 * f0.x, t1 = kv1 * f0.y, t2v = kv2 * f0.z, t3 = kv3 * f0.w;
                pm[0] = fmaf(t0, wp0.x, fmaf(t1, wp1.x, fmaf(t2v, wp2.x, fmaf(t3, wp3.x, pm[0]))));
                pm[1] = fmaf(t0, wp0.y, fmaf(t1, wp1.y, fmaf(t2v, wp2.y, fmaf(t3, wp3.y, pm[1]))));
                pm[2] = fmaf(t0, wp0.z, fmaf(t1, wp1.z, fmaf(t2v, wp2.z, fmaf(t3, wp3.z, pm[2]))));
                pm[3] = fmaf(t0, wp0.w, fmaf(t1, wp1.w, fmaf(t2v, wp2.w, fmaf(t3, wp3.w, pm[3]))));
                float s0 = kv0 * f1.x, s1 = kv1 * f1.y, s2 = kv2 * f1.z, s3 = kv3 * f1.w;
                pm[4] = fmaf(s0, wp0.x, fmaf(s1, wp1.x, fmaf(s2, wp2.x, fmaf(s3, wp3.x, pm[4]))));
                pm[5] = fmaf(s0, wp0.y, fmaf(s1, wp1.y, fmaf(s2, wp2.y, fmaf(s3, wp3.y, pm[5]))));
                pm[6] = fmaf(s0, wp0.z, fmaf(s1, wp1.z, fmaf(s2, wp2.z, fmaf(s3, wp3.z, pm[6]))));
                pm[7] = fmaf(s0, wp0.w, fmaf(s1, wp1.w, fmaf(s2, wp2.w, fmaf(s3, wp3.w, pm[7]))));
            }
        }
        #pragma unroll
        for (int v = 0; v < 8; ++v) pm[v] += __shfl_xor(pm[v], 32);
        if (hi == 0) {
            #pragma unroll
            for (int v = 0; v < 8; ++v) atomicAdd(&s_pm[e][v], pm[v]);
        }
    }
    __syncthreads();

    // ---- Drain: one global atomic per thread ----
    {
        int el = tid >> 3;
        int v  = tid & 7;
        if (s_valid[el]) {
            int b  = v >> 2;
            int oc = v & 3;
            atomicAdd(&sums[((size_t)b * NOUT + s_oi[el]) * 4 + oc], s_pm[el][v]);
        }
    }
}

__global__ __launch_bounds__(256) void gino_finalize_kernel(
    const float* __restrict__ sums,
    const float* __restrict__ cnt,
    const float* __restrict__ bp,
    float* __restrict__ out)
{
    int idx = blockIdx.x * 256 + threadIdx.x;
    if (idx >= 2 * NOUT * 4) return;
    int oc = idx & 3;
    int i  = (idx >> 2) & (NOUT - 1);
    float c = fmaxf(cnt[i], 1.0f);
    out[idx] = sums[idx] / c + bp[oc];
}

extern "C" void kernel_launch(void* const* d_in, const int* in_sizes, int n_in,
                              void* d_out, int out_size, void* d_ws, size_t ws_size,
                              hipStream_t stream) {
    const float* latent_embed   = (const float*)d_in[0];
    const float* latent_queries = (const float*)d_in[1];
    const float* output_queries = (const float*)d_in[2];
    const int*   nb_index       = (const int*)d_in[3];
    const int*   out_index      = (const int*)d_in[4];
    const float* W1 = (const float*)d_in[5];
    const float* b1 = (const float*)d_in[6];
    const float* W2 = (const float*)d_in[7];
    const float* b2 = (const float*)d_in[8];
    const float* W3 = (const float*)d_in[9];
    const float* b3 = (const float*)d_in[10];
    const float* Wp = (const float*)d_in[11];
    const float* bp = (const float*)d_in[12];

    const int E = in_sizes[3];

    // ws layout: sums(512K) | cnt(64K) | W2F(256K) | W3F(128K) | WpF(2K) | fembed(32M)
    float* sums = (float*)d_ws;
    float* cnt  = sums + 2 * NOUT * 4;
    unsigned short* W2F = (unsigned short*)(cnt + NOUT);
    unsigned short* W3F = W2F + 32 * 8 * 64 * 8;
    unsigned int*   WpF = (unsigned int*)(W3F + 16 * 8 * 64 * 8);
    unsigned short* fembed = (unsigned short*)(WpF + 128 * 4);
    const size_t base_bytes = (size_t)((char*)fembed - (char*)d_ws);
    const size_t femb_bytes = (size_t)2 * NGRID * CCH * 2;
    const bool use_f16 = ws_size >= base_bytes + femb_bytes;

    hipMemsetAsync(d_ws, 0, (size_t)(2 * NOUT * 4 + NOUT) * sizeof(float), stream);

    const int pack_blocks = (32 * 8 * 64 + 16 * 8 * 64 + 128 + 255) / 256;
    int nblk = (E + TE - 1) / TE;
    if (use_f16) {
        gino_prep_kernel<<<EMB_BLOCKS + pack_blocks, 256, 0, stream>>>(
            latent_embed, fembed, W2, W3, Wp, W2F, W3F, WpF, 1);
        gino_edge_kernel<1><<<nblk, NTHR, 0, stream>>>(
            latent_embed, fembed, latent_queries, output_queries, nb_index, out_index,
            W1, b1, b2, b3, W2F, W3F, Wp, WpF, sums, cnt, E);
    } else {
        gino_prep_kernel<<<pack_blocks, 256, 0, stream>>>(
            latent_embed, (unsigned short*)W2F /*unused*/, W2, W3, Wp, W2F, W3F, WpF, 0);
        gino_edge_kernel<0><<<nblk, NTHR, 0, stream>>>(
            latent_embed, (const unsigned short*)nullptr, latent_queries, output_queries,
            nb_index, out_index, W1, b1, b2, b3, W2F, W3F, Wp, WpF, sums, cnt, E);
    }

    gino_finalize_kernel<<<(2 * NOUT * 4 + 255) / 256, 256, 0, stream>>>(
        sums, cnt, bp, (float*)d_out);
}